// Round 17
// baseline (321.537 us; speedup 1.0000x reference)
//
#include <hip/hip_runtime.h>
#include <hip/hip_bf16.h>
#include <math.h>

#define L 4096
#define C 256
#define B 8

typedef __attribute__((ext_vector_type(8))) short bf16x8;
typedef __attribute__((ext_vector_type(8))) ushort u16x8;
typedef __attribute__((ext_vector_type(4))) float f32x4;

__device__ inline ushort f2bu(float f) { __hip_bfloat16 h = __float2bfloat16(f); return *(ushort*)&h; }
__device__ inline float bu2f(ushort u) { __hip_bfloat16 h; *(ushort*)&h = u; return __bfloat162float(h); }

// conv LDS swizzle key: period-8 in c => 2-way (free) bank aliasing (R11).
#define SWZ(c) ((((c) >> 1) & 3) << 4)

// ---------------- Kernel 1: mask compaction (single block) ----------------
__global__ __launch_bounds__(256) void compact_mask(
    const int* __restrict__ mask, int* __restrict__ counts,
    int* __restrict__ maskedOrig, int* __restrict__ unmaskOrig,
    int* __restrict__ posOf)
{
    __shared__ int smM[256], smU[256];
    int t = threadIdx.x;
    int flags[16];
    int cm = 0, cu = 0;
    for (int k = 0; k < 16; ++k) {
        int l = t * 16 + k;
        int f = mask[l] > 0;
        flags[k] = f;
        cm += f; cu += !f;
    }
    smM[t] = cm; smU[t] = cu;
    __syncthreads();
    for (int off = 1; off < 256; off <<= 1) {
        int vM = 0, vU = 0;
        if (t >= off) { vM = smM[t - off]; vU = smU[t - off]; }
        __syncthreads();
        smM[t] += vM; smU[t] += vU;
        __syncthreads();
    }
    if (t == 255) { counts[0] = smM[255]; counts[1] = smU[255]; }
    int pm = smM[t] - cm, pu = smU[t] - cu;
    for (int k = 0; k < 16; ++k) {
        int l = t * 16 + k;
        if (flags[k]) { maskedOrig[pm] = l; posOf[l] = pm; pm++; }
        else          { unmaskOrig[pu] = l; posOf[l] = pu; pu++; }
    }
}

// ---------------- Kernel 2: normalize rows of F_s -> compacted bf16 hi/lo ----------------
__global__ __launch_bounds__(256) void norm_transpose(
    const float* __restrict__ input, const int* __restrict__ mask,
    const int* __restrict__ counts, const int* __restrict__ posOf,
    ushort* __restrict__ fsnh, ushort* __restrict__ fsnl)
{
    int bx = blockIdx.x;           // 0..1023
    int b = bx >> 7;
    int l0 = (bx & 127) * 32;
    __shared__ float tile[256 * 33];
    __shared__ float part[8 * 33];
    __shared__ float denom[32];
    __shared__ int   rowdst[32];
    int t = threadIdx.x;
    int lsub = t & 31, cg = t >> 5;
    for (int cc = 0; cc < 256; cc += 8) {
        int c = cc + cg;
        tile[c * 33 + lsub] = input[((size_t)(b * 512 + 256 + c)) * L + l0 + lsub];
    }
    __syncthreads();
    float s = 0.f;
    for (int c = cg; c < 256; c += 8) { float v = tile[c * 33 + lsub]; s = fmaf(v, v, s); }
    part[cg * 33 + lsub] = s;
    __syncthreads();
    if (t < 32) {
        float s2 = 0.f;
        for (int g = 0; g < 8; ++g) s2 += part[g * 33 + t];
        denom[t] = sqrtf(s2) + 1e-8f;
        int l = l0 + t;
        int Nm = counts[0];
        rowdst[t] = (mask[l] > 0) ? posOf[l] : (Nm + posOf[l]);
    }
    __syncthreads();
    for (int ls = 0; ls < 32; ++ls) {
        int r = rowdst[ls];
        float d = denom[ls];
        float val = tile[t * 33 + ls] / d;
        ushort h = f2bu(val);
        float hf = bu2f(h);
        ushort lo = f2bu(val - hf);
        size_t o = ((size_t)b * L + r) * C + t;
        fsnh[o] = h;
        fsnl[o] = lo;
    }
}

// ---------------- Kernel 3: sim GEMM v9 (R16-proven: occupancy-raised, conflicts=0) ----------------
__global__ __launch_bounds__(256, 2) void sim_argmax_v9(
    const ushort* __restrict__ hi, const ushort* __restrict__ lo,
    const int* __restrict__ counts,
    float* __restrict__ pval, int* __restrict__ pidx)
{
    __shared__ ushort ldsB[16384];              // 32KB: hi 16KB | lo 16KB
    const int Nm = counts[0], Nu = counts[1];
    const int b = blockIdx.z;
    const int m0 = blockIdx.y * 64;
    const int nq = blockIdx.x;                  // 0..3
    const int t = threadIdx.x;
    const int w = t >> 6, l = t & 63;
    const int lm = l & 15, lk = l >> 4;
    const int key = lm << 4;

    const int nct = (Nu + 31) >> 5;             // 32-row chunks
    const int cA = (nq * nct) >> 2;
    const int cB = ((nq + 1) * nct) >> 2;

    float bestv[4]; int bestn[4];
#pragma unroll
    for (int r = 0; r < 4; ++r) { bestv[r] = -3e38f; bestn[r] = 0; }

    if (m0 < Nm && cA < cB) {
        const char* bytesH = (const char*)hi;
        const char* bytesL = (const char*)lo;
        const size_t bL = (size_t)b * L;
        char* ldsc = (char*)ldsB;

#define STAGE(cc) do { \
    size_t gb = (bL + (size_t)Nm + (size_t)(cc) * 32) * 512; \
    _Pragma("unroll") \
    for (int i = 0; i < 4; ++i) { \
        int x = i * 4096 + t * 16; \
        int sx = x ^ (((x >> 9) & 15) << 4); \
        __builtin_amdgcn_global_load_lds((const __attribute__((address_space(1))) unsigned*)(bytesH + gb + sx), \
            (__attribute__((address_space(3))) unsigned*)(ldsc + x), 16, 0, 0); \
        __builtin_amdgcn_global_load_lds((const __attribute__((address_space(1))) unsigned*)(bytesL + gb + sx), \
            (__attribute__((address_space(3))) unsigned*)(ldsc + 16384 + x), 16, 0, 0); \
    } \
} while (0)

        STAGE(cA);

        const int rA = m0 + w * 16 + lm;
        bf16x8 ah[8], al[8];
        {
            const ushort* aH = hi + (bL + rA) * C + lk * 8;
            const ushort* aL = lo + (bL + rA) * C + lk * 8;
#pragma unroll
            for (int ks = 0; ks < 8; ++ks) {
                ah[ks] = *(const bf16x8*)(aH + ks * 32);
                al[ks] = *(const bf16x8*)(aL + ks * 32);
            }
        }

        for (int c = cA; c < cB; ++c) {
            asm volatile("s_waitcnt vmcnt(0)" ::: "memory");
            __syncthreads();
            f32x4 acc[2];
            acc[0] = (f32x4){0.f, 0.f, 0.f, 0.f};
            acc[1] = (f32x4){0.f, 0.f, 0.f, 0.f};
#pragma unroll
            for (int ks = 0; ks < 8; ++ks) {
                bf16x8 bh[2], bl[2];
#pragma unroll
                for (int nf = 0; nf < 2; ++nf) {
                    int addr = (nf * 16 + lm) * 512 + ((ks * 64 + lk * 16) ^ key);
                    bh[nf] = *(const bf16x8*)(ldsc + addr);
                    bl[nf] = *(const bf16x8*)(ldsc + 16384 + addr);
                }
#pragma unroll
                for (int nf = 0; nf < 2; ++nf)
                    acc[nf] = __builtin_amdgcn_mfma_f32_16x16x32_bf16(ah[ks], bh[nf], acc[nf], 0, 0, 0);
#pragma unroll
                for (int nf = 0; nf < 2; ++nf)
                    acc[nf] = __builtin_amdgcn_mfma_f32_16x16x32_bf16(ah[ks], bl[nf], acc[nf], 0, 0, 0);
#pragma unroll
                for (int nf = 0; nf < 2; ++nf)
                    acc[nf] = __builtin_amdgcn_mfma_f32_16x16x32_bf16(al[ks], bh[nf], acc[nf], 0, 0, 0);
            }
            __syncthreads();
            if (c + 1 < cB) STAGE(c + 1);
            int nbase = c * 32;
#pragma unroll
            for (int r = 0; r < 4; ++r) {
#pragma unroll
                for (int nf = 0; nf < 2; ++nf) {
                    int n = nbase + nf * 16 + lm;
                    float v = acc[nf][r];
                    if (n < Nu && v > bestv[r]) { bestv[r] = v; bestn[r] = n; }
                }
            }
        }
#undef STAGE
    }

    if (m0 >= Nm) return;
#pragma unroll
    for (int r = 0; r < 4; ++r) {
        float bv = bestv[r]; int bn = bestn[r];
#pragma unroll
        for (int mk = 1; mk < 16; mk <<= 1) {
            float ov = __shfl_xor(bv, mk, 64);
            int   on = __shfl_xor(bn, mk, 64);
            if (ov > bv || (ov == bv && on < bn)) { bv = ov; bn = on; }
        }
        if (lm == 0) {
            int m = m0 + w * 16 + lk * 4 + r;
            size_t o = ((size_t)(b * 4096 + m)) * 4 + nq;
            pval[o] = bv; pidx[o] = bn;
        }
    }
}

// ---------------- Kernel 4: weight prep fp32 [co][ci][tau] -> bf16 [co][tau][ci] ----------------
__global__ __launch_bounds__(256) void wprep(
    const float* __restrict__ W1, const float* __restrict__ W2,
    ushort* __restrict__ W1bf, ushort* __restrict__ W2bf)
{
    int gid = blockIdx.x * 256 + threadIdx.x;
    const int N1 = 256 * 512 * 9;
    const int N2 = 256 * 256 * 9;
    if (gid < N1) {
        int ci = gid & 511; int rest = gid >> 9;
        int tau = rest % 9; int co = rest / 9;
        W1bf[gid] = f2bu(W1[((size_t)(co * 512 + ci)) * 9 + tau]);
    } else if (gid < N1 + N2) {
        int g = gid - N1;
        int ci = g & 255; int rest = g >> 8;
        int tau = rest % 9; int co = rest / 9;
        W2bf[g] = f2bu(W2[((size_t)(co * 256 + ci)) * 9 + tau]);
    }
}

// ---------------- Kernel 5: transpose F_c -> inT[b][pix][0:256] bf16 (rows of 512) ----------------
__global__ __launch_bounds__(256) void in_prep1(
    const float* __restrict__ input, ushort* __restrict__ inT)
{
    int b = blockIdx.y;
    int p0 = blockIdx.x * 32;
    __shared__ float tile[256][33];
    int t = threadIdx.x;
    int pq = t & 7;
    for (int cc = 0; cc < 256; cc += 32) {
        int ci = cc + (t >> 3);
        float4 v = *(const float4*)(input + ((size_t)(b * 512 + ci)) * L + p0 + pq * 4);
        tile[ci][pq * 4 + 0] = v.x; tile[ci][pq * 4 + 1] = v.y;
        tile[ci][pq * 4 + 2] = v.z; tile[ci][pq * 4 + 3] = v.w;
    }
    __syncthreads();
    int c8 = t & 31;
    for (int pp = 0; pp < 32; pp += 8) {
        int pixloc = pp + (t >> 5);
        u16x8 u;
#pragma unroll
        for (int j = 0; j < 8; ++j) u[j] = f2bu(tile[c8 * 8 + j][pixloc]);
        *(u16x8*)(inT + ((size_t)(b * 4096 + p0 + pixloc)) * 512 + c8 * 8) = u;
    }
}

// ---------------- Kernel 6: fuse fill (argmax-combine over 4 quarters folded in) ----------------
__global__ __launch_bounds__(256) void in_prep2(
    ushort* __restrict__ inT, const int* __restrict__ mask,
    const float* __restrict__ pval, const int* __restrict__ pidx,
    const int* __restrict__ posOf, const int* __restrict__ unmaskOrig)
{
    int gid = blockIdx.x * 256 + threadIdx.x;   // 1,048,576 total
    int c8 = gid & 31;
    int pix = (gid >> 5) & 4095;
    int b = gid >> 17;
    u16x8 out8;
    if (mask[pix] > 0) {
        int m = posOf[pix];
        size_t base = ((size_t)(b * 4096 + m)) * 4;
        float bv = pval[base]; int bn = pidx[base];
#pragma unroll
        for (int p = 1; p < 4; ++p) {
            float v = pval[base + p]; int n2 = pidx[base + p];
            if (v > bv || (v == bv && n2 < bn)) { bv = v; bn = n2; }
        }
        int n = unmaskOrig[bn];
        const ushort* rp = inT + ((size_t)(b * 4096 + pix)) * 512 + c8 * 8;
        const ushort* rn = inT + ((size_t)(b * 4096 + n)) * 512 + c8 * 8;
        u16x8 a = *(const u16x8*)rp;
        u16x8 bb = *(const u16x8*)rn;
#pragma unroll
        for (int j = 0; j < 8; ++j) out8[j] = f2bu(bu2f(a[j]) * bu2f(bb[j]));
    } else {
#pragma unroll
        for (int j = 0; j < 8; ++j) out8[j] = 0;
    }
    *(u16x8*)(inT + ((size_t)(b * 4096 + pix)) * 512 + 256 + c8 * 8) = out8;
}

// ---------------- Kernel 7: implicit-GEMM 3x3 conv via MFMA — 32-cout tiles ----------------
// cout tile 64->32: LDS 62208->43776 B => 3 blocks/CU (was 2), grid 512->1024.
// Same occupancy-for-latency lever that fixed sim (v9). Per-output MFMA order
// unchanged (tau-ascending) => bitwise-identical results.
// NORM_IN=1: apply f2bu(relu((x-m)*rs)) during the A-stage LDS write.
template<int CKROW, int NORM_IN>
__global__ __launch_bounds__(256, 2) void conv_mfma(
    const ushort* __restrict__ Abf, const ushort* __restrict__ Wbf,
    const float* __restrict__ mrsIn,
    ushort* __restrict__ outH, float* __restrict__ psum)
{
    __shared__ float4 ldsv[43776 / 16];
    char* lds = (char*)ldsv;
    char* ldsB = lds + 25344;                   // B-tile: [9 tau][32 cl][64 B]
    const int t = threadIdx.x;
    const int w = t >> 6;
    const int l = t & 63;
    const int lm = l & 15, lk = l >> 4;
    const int b = blockIdx.z;
    const int y0 = blockIdx.x * 4;
    const int c0 = blockIdx.y * 32;
    const int yw = y0 + w;
    const size_t abase = (size_t)b * 4096 * CKROW;

    f32x4 acc[4][2];
#pragma unroll
    for (int g = 0; g < 4; ++g)
#pragma unroll
        for (int nf = 0; nf < 2; ++nf) acc[g][nf] = (f32x4){0.f, 0.f, 0.f, 0.f};

    if (t < 48) {
        int r = t >> 3;
        int hX = ((t >> 2) & 1) ? 65 : 0;
        int hk = t & 3;
        *(float4*)(lds + (r * 66 + hX) * 64 + ((hk * 16) ^ SWZ(hX))) = (float4){0.f,0.f,0.f,0.f};
    }

    const int NKC = CKROW / 32;
    for (int kc = 0; kc < NKC; ++kc) {
        __syncthreads();
        {
            int x = t >> 2;
            int k8 = t & 3;
            int cX = x + 1;
            char* dbase = lds + cX * 64 + ((k8 * 16) ^ SWZ(cX));
            if (NORM_IN) {
                const float* mb = mrsIn + (size_t)b * 512 + (size_t)(kc * 32 + k8 * 8) * 2;
                float mm[8], rr[8];
#pragma unroll
                for (int j = 0; j < 8; ++j) { mm[j] = mb[2 * j]; rr[j] = mb[2 * j + 1]; }
#pragma unroll
                for (int r = 0; r < 6; ++r) {
                    int yy = y0 - 1 + r;
                    float4 ov = (float4){0.f, 0.f, 0.f, 0.f};
                    if (yy >= 0 && yy < 64) {
                        float4 v = *(const float4*)(Abf + abase + (size_t)(yy * 64 + x) * CKROW + kc * 32 + k8 * 8);
                        u16x8 u = *(u16x8*)&v;
                        u16x8 o;
#pragma unroll
                        for (int j = 0; j < 8; ++j) {
                            float z = (bu2f(u[j]) - mm[j]) * rr[j];
                            o[j] = f2bu(z > 0.f ? z : 0.f);
                        }
                        ov = *(float4*)&o;
                    }
                    *(float4*)(dbase + r * (66 * 64)) = ov;
                }
            } else {
#pragma unroll
                for (int r = 0; r < 6; ++r) {
                    int yy = y0 - 1 + r;
                    float4 v;
                    if (yy >= 0 && yy < 64)
                        v = *(const float4*)(Abf + abase + (size_t)(yy * 64 + x) * CKROW + kc * 32 + k8 * 8);
                    else
                        v = (float4){0.f, 0.f, 0.f, 0.f};
                    *(float4*)(dbase + r * (66 * 64)) = v;
                }
            }
            // B stage: 9 taus x 32 cl x 4 k8 slots; 2 threads per (cl,k8), split taus 5/4
            int cl = (t >> 2) & 31;
            int sub = t >> 7;                    // 0: taus 0-4, 1: taus 5-8
            char* dbaseB = ldsB + cl * 64 + ((k8 * 16) ^ SWZ(cl));
            const ushort* sbase = Wbf + ((size_t)(c0 + cl) * 9) * CKROW + kc * 32 + k8 * 8;
#pragma unroll
            for (int j = 0; j < 5; ++j) {
                int tau = sub * 5 + j;
                if (tau < 9)
                    *(float4*)(dbaseB + tau * (32 * 64)) = *(const float4*)(sbase + (size_t)tau * CKROW);
            }
        }
        __syncthreads();
#pragma unroll
        for (int ky = 0; ky < 3; ++ky) {
            int r = w + ky;
#pragma unroll
            for (int kx = 0; kx < 3; ++kx) {
                int tau = ky * 3 + kx;
                bf16x8 bfr[2];
#pragma unroll
                for (int nf = 0; nf < 2; ++nf) {
                    int cl = nf * 16 + lm;
                    bfr[nf] = *(bf16x8*)(ldsB + (tau * 32 + cl) * 64 + ((lk * 16) ^ SWZ(cl)));
                }
#pragma unroll
                for (int g = 0; g < 4; ++g) {
                    int aX = g * 16 + lm + kx;
                    bf16x8 afr = *(bf16x8*)(lds + (r * 66 + aX) * 64 + ((lk * 16) ^ SWZ(aX)));
#pragma unroll
                    for (int nf = 0; nf < 2; ++nf)
                        acc[g][nf] = __builtin_amdgcn_mfma_f32_16x16x32_bf16(afr, bfr[nf], acc[g][nf], 0, 0, 0);
                }
            }
        }
    }

#pragma unroll
    for (int g = 0; g < 4; ++g)
#pragma unroll
        for (int nf = 0; nf < 2; ++nf) {
            int cout = c0 + nf * 16 + lm;
#pragma unroll
            for (int r = 0; r < 4; ++r) {
                int pix = yw * 64 + g * 16 + lk * 4 + r;
                outH[((size_t)(b * 4096 + pix)) * 256 + cout] = f2bu(acc[g][nf][r]);
            }
        }

    float s[2], q[2];
#pragma unroll
    for (int nf = 0; nf < 2; ++nf) {
        float ss = 0.f, qq = 0.f;
#pragma unroll
        for (int g = 0; g < 4; ++g)
#pragma unroll
            for (int r = 0; r < 4; ++r) { float v = acc[g][nf][r]; ss += v; qq = fmaf(v, v, qq); }
        ss += __shfl_xor(ss, 16, 64); ss += __shfl_xor(ss, 32, 64);
        qq += __shfl_xor(qq, 16, 64); qq += __shfl_xor(qq, 32, 64);
        s[nf] = ss; q[nf] = qq;
    }
    __syncthreads();
    float* S = (float*)lds;
    float* Q = (float*)(lds + 512);
    if (l < 16) {
#pragma unroll
        for (int nf = 0; nf < 2; ++nf) {
            S[w * 32 + nf * 16 + l] = s[nf];
            Q[w * 32 + nf * 16 + l] = q[nf];
        }
    }
    __syncthreads();
    if (t < 32) {
        float ts = 0.f, tq = 0.f;
#pragma unroll
        for (int w2 = 0; w2 < 4; ++w2) { ts += S[w2 * 32 + t]; tq += Q[w2 * 32 + t]; }
        size_t o = (((size_t)(b * 256 + c0 + t)) * 16 + blockIdx.x) * 2;
        psum[o] = ts; psum[o + 1] = tq;
    }
}

// ---------------- Kernel 8: partials -> mean/rstd per (b, cout) ----------------
__global__ __launch_bounds__(256) void stats_reduce(
    const float* __restrict__ psum, float* __restrict__ mrs)
{
    int b = blockIdx.x;
    int c = threadIdx.x;
    float s = 0.f, q = 0.f;
    size_t base = ((size_t)(b * 256 + c)) * 16;
    for (int k = 0; k < 16; ++k) { s += psum[(base + k) * 2]; q += psum[(base + k) * 2 + 1]; }
    float mean = s * (1.f / 4096.f);
    float var = q * (1.f / 4096.f) - mean * mean;
    float rs = rsqrtf(var + 1e-5f);
    mrs[(b * 256 + c) * 2] = mean;
    mrs[(b * 256 + c) * 2 + 1] = rs;
}

// ---------------- Kernel 10: merged finalize (F_c half) + copy F_s half ----------------
__global__ __launch_bounds__(256) void finalize_fs(
    const ushort* __restrict__ resbf, const float* __restrict__ mrs,
    const float* __restrict__ input, float* __restrict__ out)
{
    __shared__ float tileT[256][33];
    int bx = blockIdx.x;
    int t = threadIdx.x;
    if (bx < 8192) {    // copy F_s half
        size_t i = (size_t)bx * 256 + t;
        size_t b = i >> 18;
        size_t r = i & 262143;
        size_t o = ((size_t)(b * 512 + 256)) * 1024 + r;
        ((float4*)out)[o] = ((const float4*)input)[o];
        return;
    }
    int fb = bx - 8192;
    int b = fb >> 7;
    int p0 = (fb & 127) * 32;
    int c8 = t & 31;
    for (int pp = 0; pp < 32; pp += 8) {
        int pixloc = pp + (t >> 5);
        u16x8 u = *(const u16x8*)(resbf + (((size_t)(b * 4096 + p0 + pixloc)) << 8) + c8 * 8);
#pragma unroll
        for (int j = 0; j < 8; ++j) tileT[c8 * 8 + j][pixloc] = bu2f(u[j]);
    }
    __syncthreads();
    int pq = t & 7;
    for (int cc = 0; cc < 256; cc += 32) {
        int c = cc + (t >> 3);
        float m = mrs[(b * 256 + c) * 2];
        float rs = mrs[(b * 256 + c) * 2 + 1];
        size_t off = ((size_t)(b * 512 + c)) * L + p0 + pq * 4;
        float4 f = *(const float4*)(input + off);
        float4 o;
        o.x = f.x + (tileT[c][pq * 4 + 0] - m) * rs;
        o.y = f.y + (tileT[c][pq * 4 + 1] - m) * rs;
        o.z = f.z + (tileT[c][pq * 4 + 2] - m) * rs;
        o.w = f.w + (tileT[c][pq * 4 + 3] - m) * rs;
        *(float4*)(out + off) = o;
    }
}

extern "C" void kernel_launch(void* const* d_in, const int* in_sizes, int n_in,
                              void* d_out, int out_size, void* d_ws, size_t ws_size,
                              hipStream_t stream) {
    const float* input = (const float*)d_in[0];
    const int*   mask  = (const int*)d_in[1];
    const float* W1    = (const float*)d_in[2];
    const float* W2    = (const float*)d_in[4];
    float* out = (float*)d_out;
    (void)in_sizes; (void)n_in; (void)out_size; (void)ws_size;

    char* ob = (char*)d_out;
    char* wp = (char*)d_ws;

    // ---- out-region overlays (phase-ordered) ----
    ushort* fsnh = (ushort*)ob;
    ushort* fsnl = (ushort*)(ob + 16777216);
    float*  pval = (float*)(ob + 33554432);
    int*    pidx = (int*)(ob + 37748736);
    ushort* inT  = (ushort*)ob;
    ushort* hraw = (ushort*)(ob + 33554432);

    // ---- ws regions (~21.1 MB) ----
    ushort* resbf  = (ushort*)wp;                        // 16,777,216
    ushort* W1bf   = (ushort*)(wp + 16777216);           //  2,359,296
    ushort* W2bf   = (ushort*)(wp + 19136512);           //  1,179,648
    float*  psum1  = (float*)(wp + 20316160);            //    262,144
    float*  psum2  = (float*)(wp + 20578304);            //    262,144
    float*  mrs1   = (float*)(wp + 20840448);            //     16,384
    float*  mrs2   = (float*)(wp + 20856832);            //     16,384
    int* counts     = (int*)(wp + 20873216);             //         16
    int* maskedOrig = counts + 4;                        //     16,384
    int* unmaskOrig = maskedOrig + L;                    //     16,384
    int* posOf      = unmaskOrig + L;                    //     16,384

    compact_mask<<<1, 256, 0, stream>>>(mask, counts, maskedOrig, unmaskOrig, posOf);
    norm_transpose<<<1024, 256, 0, stream>>>(input, mask, counts, posOf, fsnh, fsnl);
    sim_argmax_v9<<<dim3(4, 64, 8), 256, 0, stream>>>(fsnh, fsnl, counts, pval, pidx);
    wprep<<<6912, 256, 0, stream>>>(W1, W2, W1bf, W2bf);
    in_prep1<<<dim3(128, 8), 256, 0, stream>>>(input, inT);
    in_prep2<<<4096, 256, 0, stream>>>(inT, mask, pval, pidx, posOf, unmaskOrig);
    conv_mfma<512, 0><<<dim3(16, 8, 8), 256, 0, stream>>>(inT, W1bf, (const float*)nullptr, hraw, psum1);
    stats_reduce<<<8, 256, 0, stream>>>(psum1, mrs1);
    conv_mfma<256, 1><<<dim3(16, 8, 8), 256, 0, stream>>>(hraw, W2bf, mrs1, resbf, psum2);
    stats_reduce<<<8, 256, 0, stream>>>(psum2, mrs2);
    finalize_fs<<<9216, 256, 0, stream>>>(resbf, mrs2, input, out);
}

// Round 18
// 249.700 us; speedup vs baseline: 1.2877x; 1.2877x over previous
//
#include <hip/hip_runtime.h>
#include <hip/hip_bf16.h>
#include <math.h>

#define L 4096
#define C 256
#define B 8

typedef __attribute__((ext_vector_type(8))) short bf16x8;
typedef __attribute__((ext_vector_type(8))) ushort u16x8;
typedef __attribute__((ext_vector_type(4))) float f32x4;

__device__ inline ushort f2bu(float f) { __hip_bfloat16 h = __float2bfloat16(f); return *(ushort*)&h; }
__device__ inline float bu2f(ushort u) { __hip_bfloat16 h; *(ushort*)&h = u; return __bfloat162float(h); }

// conv LDS swizzle key: period-8 in c => 2-way (free) bank aliasing (R11).
#define SWZ(c) ((((c) >> 1) & 3) << 4)

// ---------------- Kernel 1: mask compaction (single block) ----------------
__global__ __launch_bounds__(256) void compact_mask(
    const int* __restrict__ mask, int* __restrict__ counts,
    int* __restrict__ maskedOrig, int* __restrict__ unmaskOrig,
    int* __restrict__ posOf)
{
    __shared__ int smM[256], smU[256];
    int t = threadIdx.x;
    int flags[16];
    int cm = 0, cu = 0;
    for (int k = 0; k < 16; ++k) {
        int l = t * 16 + k;
        int f = mask[l] > 0;
        flags[k] = f;
        cm += f; cu += !f;
    }
    smM[t] = cm; smU[t] = cu;
    __syncthreads();
    for (int off = 1; off < 256; off <<= 1) {
        int vM = 0, vU = 0;
        if (t >= off) { vM = smM[t - off]; vU = smU[t - off]; }
        __syncthreads();
        smM[t] += vM; smU[t] += vU;
        __syncthreads();
    }
    if (t == 255) { counts[0] = smM[255]; counts[1] = smU[255]; }
    int pm = smM[t] - cm, pu = smU[t] - cu;
    for (int k = 0; k < 16; ++k) {
        int l = t * 16 + k;
        if (flags[k]) { maskedOrig[pm] = l; posOf[l] = pm; pm++; }
        else          { unmaskOrig[pu] = l; posOf[l] = pu; pu++; }
    }
}

// ---------------- Kernel 2: normalize rows of F_s -> compacted bf16 hi/lo ----------------
__global__ __launch_bounds__(256) void norm_transpose(
    const float* __restrict__ input, const int* __restrict__ mask,
    const int* __restrict__ counts, const int* __restrict__ posOf,
    ushort* __restrict__ fsnh, ushort* __restrict__ fsnl)
{
    int bx = blockIdx.x;           // 0..1023
    int b = bx >> 7;
    int l0 = (bx & 127) * 32;
    __shared__ float tile[256 * 33];
    __shared__ float part[8 * 33];
    __shared__ float denom[32];
    __shared__ int   rowdst[32];
    int t = threadIdx.x;
    int lsub = t & 31, cg = t >> 5;
    for (int cc = 0; cc < 256; cc += 8) {
        int c = cc + cg;
        tile[c * 33 + lsub] = input[((size_t)(b * 512 + 256 + c)) * L + l0 + lsub];
    }
    __syncthreads();
    float s = 0.f;
    for (int c = cg; c < 256; c += 8) { float v = tile[c * 33 + lsub]; s = fmaf(v, v, s); }
    part[cg * 33 + lsub] = s;
    __syncthreads();
    if (t < 32) {
        float s2 = 0.f;
        for (int g = 0; g < 8; ++g) s2 += part[g * 33 + t];
        denom[t] = sqrtf(s2) + 1e-8f;
        int l = l0 + t;
        int Nm = counts[0];
        rowdst[t] = (mask[l] > 0) ? posOf[l] : (Nm + posOf[l]);
    }
    __syncthreads();
    for (int ls = 0; ls < 32; ++ls) {
        int r = rowdst[ls];
        float d = denom[ls];
        float val = tile[t * 33 + ls] / d;
        ushort h = f2bu(val);
        float hf = bu2f(h);
        ushort lo = f2bu(val - hf);
        size_t o = ((size_t)b * L + r) * C + t;
        fsnh[o] = h;
        fsnl[o] = lo;
    }
}

// ---------------- Kernel 3: sim GEMM v9 (R16-proven: occupancy-raised, conflicts=0) ----------------
__global__ __launch_bounds__(256, 2) void sim_argmax_v9(
    const ushort* __restrict__ hi, const ushort* __restrict__ lo,
    const int* __restrict__ counts,
    float* __restrict__ pval, int* __restrict__ pidx)
{
    __shared__ ushort ldsB[16384];              // 32KB: hi 16KB | lo 16KB
    const int Nm = counts[0], Nu = counts[1];
    const int b = blockIdx.z;
    const int m0 = blockIdx.y * 64;
    const int nq = blockIdx.x;                  // 0..3
    const int t = threadIdx.x;
    const int w = t >> 6, l = t & 63;
    const int lm = l & 15, lk = l >> 4;
    const int key = lm << 4;

    const int nct = (Nu + 31) >> 5;             // 32-row chunks
    const int cA = (nq * nct) >> 2;
    const int cB = ((nq + 1) * nct) >> 2;

    float bestv[4]; int bestn[4];
#pragma unroll
    for (int r = 0; r < 4; ++r) { bestv[r] = -3e38f; bestn[r] = 0; }

    if (m0 < Nm && cA < cB) {
        const char* bytesH = (const char*)hi;
        const char* bytesL = (const char*)lo;
        const size_t bL = (size_t)b * L;
        char* ldsc = (char*)ldsB;

#define STAGE(cc) do { \
    size_t gb = (bL + (size_t)Nm + (size_t)(cc) * 32) * 512; \
    _Pragma("unroll") \
    for (int i = 0; i < 4; ++i) { \
        int x = i * 4096 + t * 16; \
        int sx = x ^ (((x >> 9) & 15) << 4); \
        __builtin_amdgcn_global_load_lds((const __attribute__((address_space(1))) unsigned*)(bytesH + gb + sx), \
            (__attribute__((address_space(3))) unsigned*)(ldsc + x), 16, 0, 0); \
        __builtin_amdgcn_global_load_lds((const __attribute__((address_space(1))) unsigned*)(bytesL + gb + sx), \
            (__attribute__((address_space(3))) unsigned*)(ldsc + 16384 + x), 16, 0, 0); \
    } \
} while (0)

        STAGE(cA);

        const int rA = m0 + w * 16 + lm;
        bf16x8 ah[8], al[8];
        {
            const ushort* aH = hi + (bL + rA) * C + lk * 8;
            const ushort* aL = lo + (bL + rA) * C + lk * 8;
#pragma unroll
            for (int ks = 0; ks < 8; ++ks) {
                ah[ks] = *(const bf16x8*)(aH + ks * 32);
                al[ks] = *(const bf16x8*)(aL + ks * 32);
            }
        }

        for (int c = cA; c < cB; ++c) {
            asm volatile("s_waitcnt vmcnt(0)" ::: "memory");
            __syncthreads();
            f32x4 acc[2];
            acc[0] = (f32x4){0.f, 0.f, 0.f, 0.f};
            acc[1] = (f32x4){0.f, 0.f, 0.f, 0.f};
#pragma unroll
            for (int ks = 0; ks < 8; ++ks) {
                bf16x8 bh[2], bl[2];
#pragma unroll
                for (int nf = 0; nf < 2; ++nf) {
                    int addr = (nf * 16 + lm) * 512 + ((ks * 64 + lk * 16) ^ key);
                    bh[nf] = *(const bf16x8*)(ldsc + addr);
                    bl[nf] = *(const bf16x8*)(ldsc + 16384 + addr);
                }
#pragma unroll
                for (int nf = 0; nf < 2; ++nf)
                    acc[nf] = __builtin_amdgcn_mfma_f32_16x16x32_bf16(ah[ks], bh[nf], acc[nf], 0, 0, 0);
#pragma unroll
                for (int nf = 0; nf < 2; ++nf)
                    acc[nf] = __builtin_amdgcn_mfma_f32_16x16x32_bf16(ah[ks], bl[nf], acc[nf], 0, 0, 0);
#pragma unroll
                for (int nf = 0; nf < 2; ++nf)
                    acc[nf] = __builtin_amdgcn_mfma_f32_16x16x32_bf16(al[ks], bh[nf], acc[nf], 0, 0, 0);
            }
            __syncthreads();
            if (c + 1 < cB) STAGE(c + 1);
            int nbase = c * 32;
#pragma unroll
            for (int r = 0; r < 4; ++r) {
#pragma unroll
                for (int nf = 0; nf < 2; ++nf) {
                    int n = nbase + nf * 16 + lm;
                    float v = acc[nf][r];
                    if (n < Nu && v > bestv[r]) { bestv[r] = v; bestn[r] = n; }
                }
            }
        }
#undef STAGE
    }

    if (m0 >= Nm) return;
#pragma unroll
    for (int r = 0; r < 4; ++r) {
        float bv = bestv[r]; int bn = bestn[r];
#pragma unroll
        for (int mk = 1; mk < 16; mk <<= 1) {
            float ov = __shfl_xor(bv, mk, 64);
            int   on = __shfl_xor(bn, mk, 64);
            if (ov > bv || (ov == bv && on < bn)) { bv = ov; bn = on; }
        }
        if (lm == 0) {
            int m = m0 + w * 16 + lk * 4 + r;
            size_t o = ((size_t)(b * 4096 + m)) * 4 + nq;
            pval[o] = bv; pidx[o] = bn;
        }
    }
}

// ---------------- Kernel 4: weight prep fp32 [co][ci][tau] -> bf16 [co][tau][ci] ----------------
__global__ __launch_bounds__(256) void wprep(
    const float* __restrict__ W1, const float* __restrict__ W2,
    ushort* __restrict__ W1bf, ushort* __restrict__ W2bf)
{
    int gid = blockIdx.x * 256 + threadIdx.x;
    const int N1 = 256 * 512 * 9;
    const int N2 = 256 * 256 * 9;
    if (gid < N1) {
        int ci = gid & 511; int rest = gid >> 9;
        int tau = rest % 9; int co = rest / 9;
        W1bf[gid] = f2bu(W1[((size_t)(co * 512 + ci)) * 9 + tau]);
    } else if (gid < N1 + N2) {
        int g = gid - N1;
        int ci = g & 255; int rest = g >> 8;
        int tau = rest % 9; int co = rest / 9;
        W2bf[g] = f2bu(W2[((size_t)(co * 256 + ci)) * 9 + tau]);
    }
}

// ---------------- Kernel 5: transpose F_c -> inT[b][pix][0:256] bf16 (rows of 512) ----------------
__global__ __launch_bounds__(256) void in_prep1(
    const float* __restrict__ input, ushort* __restrict__ inT)
{
    int b = blockIdx.y;
    int p0 = blockIdx.x * 32;
    __shared__ float tile[256][33];
    int t = threadIdx.x;
    int pq = t & 7;
    for (int cc = 0; cc < 256; cc += 32) {
        int ci = cc + (t >> 3);
        float4 v = *(const float4*)(input + ((size_t)(b * 512 + ci)) * L + p0 + pq * 4);
        tile[ci][pq * 4 + 0] = v.x; tile[ci][pq * 4 + 1] = v.y;
        tile[ci][pq * 4 + 2] = v.z; tile[ci][pq * 4 + 3] = v.w;
    }
    __syncthreads();
    int c8 = t & 31;
    for (int pp = 0; pp < 32; pp += 8) {
        int pixloc = pp + (t >> 5);
        u16x8 u;
#pragma unroll
        for (int j = 0; j < 8; ++j) u[j] = f2bu(tile[c8 * 8 + j][pixloc]);
        *(u16x8*)(inT + ((size_t)(b * 4096 + p0 + pixloc)) * 512 + c8 * 8) = u;
    }
}

// ---------------- Kernel 6: fuse fill (argmax-combine over 4 quarters folded in) ----------------
__global__ __launch_bounds__(256) void in_prep2(
    ushort* __restrict__ inT, const int* __restrict__ mask,
    const float* __restrict__ pval, const int* __restrict__ pidx,
    const int* __restrict__ posOf, const int* __restrict__ unmaskOrig)
{
    int gid = blockIdx.x * 256 + threadIdx.x;   // 1,048,576 total
    int c8 = gid & 31;
    int pix = (gid >> 5) & 4095;
    int b = gid >> 17;
    u16x8 out8;
    if (mask[pix] > 0) {
        int m = posOf[pix];
        size_t base = ((size_t)(b * 4096 + m)) * 4;
        float bv = pval[base]; int bn = pidx[base];
#pragma unroll
        for (int p = 1; p < 4; ++p) {
            float v = pval[base + p]; int n2 = pidx[base + p];
            if (v > bv || (v == bv && n2 < bn)) { bv = v; bn = n2; }
        }
        int n = unmaskOrig[bn];
        const ushort* rp = inT + ((size_t)(b * 4096 + pix)) * 512 + c8 * 8;
        const ushort* rn = inT + ((size_t)(b * 4096 + n)) * 512 + c8 * 8;
        u16x8 a = *(const u16x8*)rp;
        u16x8 bb = *(const u16x8*)rn;
#pragma unroll
        for (int j = 0; j < 8; ++j) out8[j] = f2bu(bu2f(a[j]) * bu2f(bb[j]));
    } else {
#pragma unroll
        for (int j = 0; j < 8; ++j) out8[j] = 0;
    }
    *(u16x8*)(inT + ((size_t)(b * 4096 + pix)) * 512 + 256 + c8 * 8) = out8;
}

// ---------------- Kernel 7: implicit-GEMM 3x3 conv via MFMA (R16-proven 64-cout tiles) ----------------
// NORM_IN=1: apply f2bu(relu((x-m)*rs)) during the A-stage LDS write (fused norm1_apply).
template<int CKROW, int NORM_IN>
__global__ __launch_bounds__(256, 2) void conv_mfma(
    const ushort* __restrict__ Abf, const ushort* __restrict__ Wbf,
    const float* __restrict__ mrsIn,
    ushort* __restrict__ outH, float* __restrict__ psum)
{
    __shared__ float4 ldsv[62208 / 16];
    char* lds = (char*)ldsv;
    char* ldsB = lds + 25344;
    const int t = threadIdx.x;
    const int w = t >> 6;
    const int l = t & 63;
    const int lm = l & 15, lk = l >> 4;
    const int b = blockIdx.z;
    const int y0 = blockIdx.x * 4;
    const int c0 = blockIdx.y * 64;
    const int yw = y0 + w;
    const size_t abase = (size_t)b * 4096 * CKROW;

    f32x4 acc[4][4];
#pragma unroll
    for (int g = 0; g < 4; ++g)
#pragma unroll
        for (int nf = 0; nf < 4; ++nf) acc[g][nf] = (f32x4){0.f, 0.f, 0.f, 0.f};

    if (t < 48) {
        int r = t >> 3;
        int hX = ((t >> 2) & 1) ? 65 : 0;
        int hk = t & 3;
        *(float4*)(lds + (r * 66 + hX) * 64 + ((hk * 16) ^ SWZ(hX))) = (float4){0.f,0.f,0.f,0.f};
    }

    const int NKC = CKROW / 32;
    for (int kc = 0; kc < NKC; ++kc) {
        __syncthreads();
        {
            int x = t >> 2;
            int k8 = t & 3;
            int cX = x + 1;
            char* dbase = lds + cX * 64 + ((k8 * 16) ^ SWZ(cX));
            if (NORM_IN) {
                const float* mb = mrsIn + (size_t)b * 512 + (size_t)(kc * 32 + k8 * 8) * 2;
                float mm[8], rr[8];
#pragma unroll
                for (int j = 0; j < 8; ++j) { mm[j] = mb[2 * j]; rr[j] = mb[2 * j + 1]; }
#pragma unroll
                for (int r = 0; r < 6; ++r) {
                    int yy = y0 - 1 + r;
                    float4 ov = (float4){0.f, 0.f, 0.f, 0.f};
                    if (yy >= 0 && yy < 64) {
                        float4 v = *(const float4*)(Abf + abase + (size_t)(yy * 64 + x) * CKROW + kc * 32 + k8 * 8);
                        u16x8 u = *(u16x8*)&v;
                        u16x8 o;
#pragma unroll
                        for (int j = 0; j < 8; ++j) {
                            float z = (bu2f(u[j]) - mm[j]) * rr[j];
                            o[j] = f2bu(z > 0.f ? z : 0.f);
                        }
                        ov = *(float4*)&o;
                    }
                    *(float4*)(dbase + r * (66 * 64)) = ov;
                }
            } else {
#pragma unroll
                for (int r = 0; r < 6; ++r) {
                    int yy = y0 - 1 + r;
                    float4 v;
                    if (yy >= 0 && yy < 64)
                        v = *(const float4*)(Abf + abase + (size_t)(yy * 64 + x) * CKROW + kc * 32 + k8 * 8);
                    else
                        v = (float4){0.f, 0.f, 0.f, 0.f};
                    *(float4*)(dbase + r * (66 * 64)) = v;
                }
            }
            int cl = t >> 2;
            char* dbaseB = ldsB + cl * 64 + ((k8 * 16) ^ SWZ(cl));
            const ushort* sbase = Wbf + ((size_t)(c0 + cl) * 9) * CKROW + kc * 32 + k8 * 8;
#pragma unroll
            for (int tau = 0; tau < 9; ++tau) {
                *(float4*)(dbaseB + tau * (64 * 64)) = *(const float4*)(sbase + (size_t)tau * CKROW);
            }
        }
        __syncthreads();
#pragma unroll
        for (int ky = 0; ky < 3; ++ky) {
            int r = w + ky;
#pragma unroll
            for (int kx = 0; kx < 3; ++kx) {
                int tau = ky * 3 + kx;
                bf16x8 bfr[4];
#pragma unroll
                for (int nf = 0; nf < 4; ++nf) {
                    int cl = nf * 16 + lm;
                    bfr[nf] = *(bf16x8*)(ldsB + (tau * 64 + cl) * 64 + ((lk * 16) ^ SWZ(cl)));
                }
#pragma unroll
                for (int g = 0; g < 4; ++g) {
                    int aX = g * 16 + lm + kx;
                    bf16x8 afr = *(bf16x8*)(lds + (r * 66 + aX) * 64 + ((lk * 16) ^ SWZ(aX)));
#pragma unroll
                    for (int nf = 0; nf < 4; ++nf)
                        acc[g][nf] = __builtin_amdgcn_mfma_f32_16x16x32_bf16(afr, bfr[nf], acc[g][nf], 0, 0, 0);
                }
            }
        }
    }

#pragma unroll
    for (int g = 0; g < 4; ++g)
#pragma unroll
        for (int nf = 0; nf < 4; ++nf) {
            int cout = c0 + nf * 16 + lm;
#pragma unroll
            for (int r = 0; r < 4; ++r) {
                int pix = yw * 64 + g * 16 + lk * 4 + r;
                outH[((size_t)(b * 4096 + pix)) * 256 + cout] = f2bu(acc[g][nf][r]);
            }
        }

    float s[4], q[4];
#pragma unroll
    for (int nf = 0; nf < 4; ++nf) {
        float ss = 0.f, qq = 0.f;
#pragma unroll
        for (int g = 0; g < 4; ++g)
#pragma unroll
            for (int r = 0; r < 4; ++r) { float v = acc[g][nf][r]; ss += v; qq = fmaf(v, v, qq); }
        ss += __shfl_xor(ss, 16, 64); ss += __shfl_xor(ss, 32, 64);
        qq += __shfl_xor(qq, 16, 64); qq += __shfl_xor(qq, 32, 64);
        s[nf] = ss; q[nf] = qq;
    }
    __syncthreads();
    float* S = (float*)lds;
    float* Q = (float*)(lds + 1024);
    if (l < 16) {
#pragma unroll
        for (int nf = 0; nf < 4; ++nf) {
            S[w * 64 + nf * 16 + l] = s[nf];
            Q[w * 64 + nf * 16 + l] = q[nf];
        }
    }
    __syncthreads();
    if (t < 64) {
        float ts = 0.f, tq = 0.f;
#pragma unroll
        for (int w2 = 0; w2 < 4; ++w2) { ts += S[w2 * 64 + t]; tq += Q[w2 * 64 + t]; }
        size_t o = (((size_t)(b * 256 + c0 + t)) * 16 + blockIdx.x) * 2;
        psum[o] = ts; psum[o + 1] = tq;
    }
}

// ---------------- Kernel 8: partials -> mean/rstd per (b, cout) ----------------
__global__ __launch_bounds__(256) void stats_reduce(
    const float* __restrict__ psum, float* __restrict__ mrs)
{
    int b = blockIdx.x;
    int c = threadIdx.x;
    float s = 0.f, q = 0.f;
    size_t base = ((size_t)(b * 256 + c)) * 16;
    for (int k = 0; k < 16; ++k) { s += psum[(base + k) * 2]; q += psum[(base + k) * 2 + 1]; }
    float mean = s * (1.f / 4096.f);
    float var = q * (1.f / 4096.f) - mean * mean;
    float rs = rsqrtf(var + 1e-5f);
    mrs[(b * 256 + c) * 2] = mean;
    mrs[(b * 256 + c) * 2 + 1] = rs;
}

// ---------------- Kernel 10: merged finalize (F_c half) + copy F_s half ----------------
__global__ __launch_bounds__(256) void finalize_fs(
    const ushort* __restrict__ resbf, const float* __restrict__ mrs,
    const float* __restrict__ input, float* __restrict__ out)
{
    __shared__ float tileT[256][33];
    int bx = blockIdx.x;
    int t = threadIdx.x;
    if (bx < 8192) {    // copy F_s half
        size_t i = (size_t)bx * 256 + t;
        size_t b = i >> 18;
        size_t r = i & 262143;
        size_t o = ((size_t)(b * 512 + 256)) * 1024 + r;
        ((float4*)out)[o] = ((const float4*)input)[o];
        return;
    }
    int fb = bx - 8192;
    int b = fb >> 7;
    int p0 = (fb & 127) * 32;
    int c8 = t & 31;
    for (int pp = 0; pp < 32; pp += 8) {
        int pixloc = pp + (t >> 5);
        u16x8 u = *(const u16x8*)(resbf + (((size_t)(b * 4096 + p0 + pixloc)) << 8) + c8 * 8);
#pragma unroll
        for (int j = 0; j < 8; ++j) tileT[c8 * 8 + j][pixloc] = bu2f(u[j]);
    }
    __syncthreads();
    int pq = t & 7;
    for (int cc = 0; cc < 256; cc += 32) {
        int c = cc + (t >> 3);
        float m = mrs[(b * 256 + c) * 2];
        float rs = mrs[(b * 256 + c) * 2 + 1];
        size_t off = ((size_t)(b * 512 + c)) * L + p0 + pq * 4;
        float4 f = *(const float4*)(input + off);
        float4 o;
        o.x = f.x + (tileT[c][pq * 4 + 0] - m) * rs;
        o.y = f.y + (tileT[c][pq * 4 + 1] - m) * rs;
        o.z = f.z + (tileT[c][pq * 4 + 2] - m) * rs;
        o.w = f.w + (tileT[c][pq * 4 + 3] - m) * rs;
        *(float4*)(out + off) = o;
    }
}

extern "C" void kernel_launch(void* const* d_in, const int* in_sizes, int n_in,
                              void* d_out, int out_size, void* d_ws, size_t ws_size,
                              hipStream_t stream) {
    const float* input = (const float*)d_in[0];
    const int*   mask  = (const int*)d_in[1];
    const float* W1    = (const float*)d_in[2];
    const float* W2    = (const float*)d_in[4];
    float* out = (float*)d_out;
    (void)in_sizes; (void)n_in; (void)out_size; (void)ws_size;

    char* ob = (char*)d_out;
    char* wp = (char*)d_ws;

    // ---- out-region overlays (phase-ordered) ----
    ushort* fsnh = (ushort*)ob;
    ushort* fsnl = (ushort*)(ob + 16777216);
    float*  pval = (float*)(ob + 33554432);
    int*    pidx = (int*)(ob + 37748736);
    ushort* inT  = (ushort*)ob;
    ushort* hraw = (ushort*)(ob + 33554432);

    // ---- ws regions (~21.1 MB) ----
    ushort* resbf  = (ushort*)wp;                        // 16,777,216
    ushort* W1bf   = (ushort*)(wp + 16777216);           //  2,359,296
    ushort* W2bf   = (ushort*)(wp + 19136512);           //  1,179,648
    float*  psum1  = (float*)(wp + 20316160);            //    262,144
    float*  psum2  = (float*)(wp + 20578304);            //    262,144
    float*  mrs1   = (float*)(wp + 20840448);            //     16,384
    float*  mrs2   = (float*)(wp + 20856832);            //     16,384
    int* counts     = (int*)(wp + 20873216);             //         16
    int* maskedOrig = counts + 4;                        //     16,384
    int* unmaskOrig = maskedOrig + L;                    //     16,384
    int* posOf      = unmaskOrig + L;                    //     16,384

    compact_mask<<<1, 256, 0, stream>>>(mask, counts, maskedOrig, unmaskOrig, posOf);
    norm_transpose<<<1024, 256, 0, stream>>>(input, mask, counts, posOf, fsnh, fsnl);
    sim_argmax_v9<<<dim3(4, 64, 8), 256, 0, stream>>>(fsnh, fsnl, counts, pval, pidx);
    wprep<<<6912, 256, 0, stream>>>(W1, W2, W1bf, W2bf);
    in_prep1<<<dim3(128, 8), 256, 0, stream>>>(input, inT);
    in_prep2<<<4096, 256, 0, stream>>>(inT, mask, pval, pidx, posOf, unmaskOrig);
    conv_mfma<512, 0><<<dim3(16, 4, 8), 256, 0, stream>>>(inT, W1bf, (const float*)nullptr, hraw, psum1);
    stats_reduce<<<8, 256, 0, stream>>>(psum1, mrs1);
    conv_mfma<256, 1><<<dim3(16, 4, 8), 256, 0, stream>>>(hraw, W2bf, mrs1, resbf, psum2);
    stats_reduce<<<8, 256, 0, stream>>>(psum2, mrs2);
    finalize_fs<<<9216, 256, 0, stream>>>(resbf, mrs2, input, out);
}